// Round 1
// baseline (1470.788 us; speedup 1.0000x reference)
//
#include <hip/hip_runtime.h>
#include <cstdint>

#define T_STEPS 250
#define BATCH   256
#define NI      700
#define NH      1024
#define NO      20
#define BETAF   0.9f

// ---------------------------------------------------------------------------
// K0: zero LIF state, build W2T[h][o] (transpose of W2[o][h]) for coalesced
//     20-lane reads in fc2.
// ---------------------------------------------------------------------------
__global__ __launch_bounds__(256) void k0_init(const float* __restrict__ W2,
                                               float* __restrict__ W2T,
                                               float* __restrict__ mem1) {
    int idx = blockIdx.x * 256 + threadIdx.x;
    if (idx < BATCH * NH) mem1[idx] = 0.f;
    if (idx < NH * NO) {
        int h = idx / NO, o = idx % NO;
        W2T[idx] = W2[o * NH + h];
    }
}

// ---------------------------------------------------------------------------
// K2: fc1 GEMM  C[m,n] = sum_k A[m,k] * W1[n,k]
//   A: [Mrows, 700] fp32 (binary spikes), W1: [1024, 700] fp32, C: [Mrows,1024]
//   64x64 tile, BK=32, 256 threads, 4x4 microtile, ascending-k single
//   accumulator chain (deterministic, matches "natural" summation order).
// ---------------------------------------------------------------------------
__global__ __launch_bounds__(256) void k2_fc1(const float* __restrict__ A,
                                              const float* __restrict__ W1,
                                              float* __restrict__ C) {
    __shared__ float As[32 * 64];  // [k][m]
    __shared__ float Bs[32 * 64];  // [k][n]
    const int tid = threadIdx.x;
    const int bm = blockIdx.x * 64;
    const int bn = blockIdx.y * 64;
    const int tm = tid >> 4;       // 0..15  -> m micro-row
    const int tn = tid & 15;       // 0..15  -> n micro-col
    const int f0 = tid * 2, f1 = f0 + 1;   // two float4 stage slots / thread

    auto ld = [&](const float* __restrict__ P, int baseRow, int f, int kt) -> float4 {
        int ml = f >> 3;                       // row within tile (8 float4 per 32-k row)
        int kg = kt * 32 + ((f & 7) << 2);     // global k (multiple of 4; 700%4==0)
        if (kg < NI)
            return *(const float4*)(P + (baseRow + ml) * NI + kg);
        return make_float4(0.f, 0.f, 0.f, 0.f);
    };

    float acc[4][4];
#pragma unroll
    for (int i = 0; i < 4; ++i)
#pragma unroll
        for (int j = 0; j < 4; ++j) acc[i][j] = 0.f;

    float4 pa0 = ld(A, bm, f0, 0), pa1 = ld(A, bm, f1, 0);
    float4 pb0 = ld(W1, bn, f0, 0), pb1 = ld(W1, bn, f1, 0);

    const int NT = (NI + 31) / 32;  // 22 (last tile zero-padded; adds exact +0.0)
    for (int kt = 0; kt < NT; ++kt) {
        __syncthreads();
        {
            int ml0 = f0 >> 3, kq0 = (f0 & 7) << 2;
            As[(kq0 + 0) * 64 + ml0] = pa0.x; As[(kq0 + 1) * 64 + ml0] = pa0.y;
            As[(kq0 + 2) * 64 + ml0] = pa0.z; As[(kq0 + 3) * 64 + ml0] = pa0.w;
            Bs[(kq0 + 0) * 64 + ml0] = pb0.x; Bs[(kq0 + 1) * 64 + ml0] = pb0.y;
            Bs[(kq0 + 2) * 64 + ml0] = pb0.z; Bs[(kq0 + 3) * 64 + ml0] = pb0.w;
            int ml1 = f1 >> 3, kq1 = (f1 & 7) << 2;
            As[(kq1 + 0) * 64 + ml1] = pa1.x; As[(kq1 + 1) * 64 + ml1] = pa1.y;
            As[(kq1 + 2) * 64 + ml1] = pa1.z; As[(kq1 + 3) * 64 + ml1] = pa1.w;
            Bs[(kq1 + 0) * 64 + ml1] = pb1.x; Bs[(kq1 + 1) * 64 + ml1] = pb1.y;
            Bs[(kq1 + 2) * 64 + ml1] = pb1.z; Bs[(kq1 + 3) * 64 + ml1] = pb1.w;
        }
        if (kt + 1 < NT) {
            pa0 = ld(A, bm, f0, kt + 1); pa1 = ld(A, bm, f1, kt + 1);
            pb0 = ld(W1, bn, f0, kt + 1); pb1 = ld(W1, bn, f1, kt + 1);
        }
        __syncthreads();
#pragma unroll
        for (int k = 0; k < 32; ++k) {
            float4 av = *(const float4*)&As[k * 64 + tm * 4];
            float4 bv = *(const float4*)&Bs[k * 64 + tn * 4];
            float aa[4] = {av.x, av.y, av.z, av.w};
            float bb[4] = {bv.x, bv.y, bv.z, bv.w};
#pragma unroll
            for (int i = 0; i < 4; ++i)
#pragma unroll
                for (int j = 0; j < 4; ++j)
                    acc[i][j] = fmaf(aa[i], bb[j], acc[i][j]);
        }
    }

#pragma unroll
    for (int i = 0; i < 4; ++i) {
        float4 v = make_float4(acc[i][0], acc[i][1], acc[i][2], acc[i][3]);
        *(float4*)(C + (bm + tm * 4 + i) * NH + bn + tn * 4) = v;
    }
}

// ---------------------------------------------------------------------------
// K3: LIF scan over a T-chunk. One thread per (b,h); mem private in register;
//     spikes emitted as per-wave 64-bit ballot masks. No barriers.
//     grid: 1024 blocks (b*4 + hgroup) x 256 threads.
// ---------------------------------------------------------------------------
__global__ __launch_bounds__(256) void k3_lif(const float* __restrict__ cur1,
                                              float* __restrict__ mem1,
                                              unsigned long long* __restrict__ bits,
                                              int TC) {
    int b = blockIdx.x >> 2;
    int hg = blockIdx.x & 3;
    int h = hg * 256 + threadIdx.x;
    int w = threadIdx.x >> 6;
    float mem = mem1[b * NH + h];
    for (int tc = 0; tc < TC; ++tc) {
        float c = cur1[(tc * BATCH + b) * NH + h];
        float reset = (mem > 1.0f) ? 1.0f : 0.0f;   // spike(mem_prev - THR)
        mem = fmaf(BETAF, mem, c) - reset;
        bool spk = mem > 1.0f;                       // mem-1 sign == (mem>1) exactly
        unsigned long long msk = __ballot(spk);
        if ((threadIdx.x & 63) == 0)
            bits[(size_t)(tc * BATCH + b) * 16 + hg * 4 + w] = msk;
    }
    mem1[b * NH + h] = mem;
}

// ---------------------------------------------------------------------------
// K4: fc2 as sparse gather over spike bitmasks. One wave per (t,b) row.
//     cur2[row, o] = sum over set bits h (ascending) of W2T[h][o].
// ---------------------------------------------------------------------------
__global__ __launch_bounds__(256) void k4_fc2(const unsigned long long* __restrict__ bits,
                                              const float* __restrict__ W2T,
                                              float* __restrict__ cur2) {
    int row = blockIdx.x * 4 + (threadIdx.x >> 6);
    int lane = threadIdx.x & 63;
    unsigned long long mv = (lane < 16) ? bits[(size_t)row * 16 + lane] : 0ULL;
    float p = 0.f;
#pragma unroll 1
    for (int wseg = 0; wseg < 16; ++wseg) {
        unsigned long long m = __shfl(mv, wseg);
        while (m) {
            int bit = __ffsll((unsigned long long)m) - 1;
            m &= m - 1;
            int h = wseg * 64 + bit;
            if (lane < NO) p += W2T[h * NO + lane];
        }
    }
    if (lane < NO) cur2[(size_t)row * NO + lane] = p;
}

// ---------------------------------------------------------------------------
// K5: leaky readout scan (no reset) + softmax over the 20 outputs.
//     32-lane subgroups: lanes 0..19 = outputs of one batch element.
// ---------------------------------------------------------------------------
__global__ __launch_bounds__(256) void k5_readout(const float* __restrict__ cur2,
                                                  float* __restrict__ out_mem,
                                                  float* __restrict__ out_sm) {
    int b = blockIdx.x * 8 + (threadIdx.x >> 5);
    int o = threadIdx.x & 31;
    bool act = o < NO;
    float mem = 0.f;
    for (int t = 0; t < T_STEPS; ++t) {
        int base = (t * BATCH + b) * NO;
        float c = act ? cur2[base + o] : 0.f;
        mem = fmaf(BETAF, mem, c);
        float mx = act ? mem : -3.4e38f;
#pragma unroll
        for (int off = 16; off; off >>= 1) mx = fmaxf(mx, __shfl_xor(mx, off, 32));
        float p = act ? expf(mem - mx) : 0.f;
        float s = p;
#pragma unroll
        for (int off = 16; off; off >>= 1) s += __shfl_xor(s, off, 32);
        if (act) {
            out_mem[base + o] = mem;
            out_sm[base + o] = p / s;
        }
    }
}

// ---------------------------------------------------------------------------
extern "C" void kernel_launch(void* const* d_in, const int* in_sizes, int n_in,
                              void* d_out, int out_size, void* d_ws, size_t ws_size,
                              hipStream_t stream) {
    const float* spikes = (const float*)d_in[0];   // [250,256,700]
    const float* W1     = (const float*)d_in[1];   // [1024,700]
    const float* W2     = (const float*)d_in[2];   // [20,1024]
    float* out_mem = (float*)d_out;                              // [250,256,20]
    float* out_sm  = out_mem + (size_t)T_STEPS * BATCH * NO;     // [250,256,20]

    char* ws = (char*)d_ws;
    size_t off = 0;
    auto alloc = [&](size_t bytes) -> char* {
        off = (off + 255) & ~(size_t)255;
        char* p = ws + off;
        off += bytes;
        return p;
    };
    float* W2T  = (float*)alloc((size_t)NH * NO * 4);
    float* mem1 = (float*)alloc((size_t)BATCH * NH * 4);
    float* cur2 = (float*)alloc((size_t)T_STEPS * BATCH * NO * 4);

    // T-chunking: cur1 (1 MB/step) + bitmasks (32 KB/step) must fit remaining ws.
    size_t fixed = (off + 255) & ~(size_t)255;
    size_t rem = ws_size > fixed ? ws_size - fixed : 0;
    size_t per_t = (size_t)BATCH * NH * 4 + (size_t)BATCH * 16 * 8 + 512;
    int TC = (int)(rem / per_t);
    if (TC > T_STEPS) TC = T_STEPS;
    if (TC < 1) TC = 1;
    float* cur1 = (float*)alloc((size_t)TC * BATCH * NH * 4);
    unsigned long long* bits = (unsigned long long*)alloc((size_t)TC * BATCH * 16 * 8);

    k0_init<<<1024, 256, 0, stream>>>(W2, W2T, mem1);

    for (int t0 = 0; t0 < T_STEPS; t0 += TC) {
        int tc = T_STEPS - t0 < TC ? T_STEPS - t0 : TC;
        dim3 g2(tc * 4, 16);  // (tc*256)/64 M-tiles x 16 N-tiles
        k2_fc1<<<g2, 256, 0, stream>>>(spikes + (size_t)t0 * BATCH * NI, W1, cur1);
        k3_lif<<<1024, 256, 0, stream>>>(cur1, mem1, bits, tc);
        k4_fc2<<<tc * 64, 256, 0, stream>>>(bits, W2T, cur2 + (size_t)t0 * BATCH * NO);
    }

    k5_readout<<<32, 256, 0, stream>>>(cur2, out_mem, out_sm);
}

// Round 2
// 699.322 us; speedup vs baseline: 2.1032x; 2.1032x over previous
//
#include <hip/hip_runtime.h>
#include <hip/hip_bf16.h>
#include <cstdint>

#define T_STEPS 250
#define BATCH   256
#define NI      700
#define NH      1024
#define NO      20
#define BETAF   0.9f
#define KPAD    704          // 22 * 32
#define KT_N    22
#define KCAT    2112         // 3 * KPAD

typedef __attribute__((ext_vector_type(8))) short bf16x8;
typedef __attribute__((ext_vector_type(4))) float f32x4;

static __device__ __forceinline__ unsigned short f2bu(float x) {
    union { __hip_bfloat16 h; unsigned short u; } c;
    c.h = __float2bfloat16(x);
    return c.u;
}
static __device__ __forceinline__ float b2f(unsigned short u) {
    union { __hip_bfloat16 h; unsigned short u; } c;
    c.u = u;
    return __bfloat162float(c.h);
}

// ---------------------------------------------------------------------------
// K0: zero LIF state; W2T[h][o]; Bcat = [hi|mid|lo] bf16 split of W1,
//     padded K 700->704. Bcat[n][s*704+k].
// ---------------------------------------------------------------------------
__global__ __launch_bounds__(256) void k0_init(const float* __restrict__ W1,
                                               const float* __restrict__ W2,
                                               float* __restrict__ W2T,
                                               float* __restrict__ mem1,
                                               unsigned short* __restrict__ Bcat) {
    int idx = blockIdx.x * 256 + threadIdx.x;
    if (idx < BATCH * NH) mem1[idx] = 0.f;
    if (idx < NH * NO) {
        int h = idx / NO, o = idx % NO;
        W2T[idx] = W2[o * NH + h];
    }
    if (idx < NH * KPAD) {
        int n = idx / KPAD, k = idx % KPAD;
        float w = (k < NI) ? W1[n * NI + k] : 0.f;
        unsigned short hu = f2bu(w);
        float r1 = w - b2f(hu);
        unsigned short mu = f2bu(r1);
        float r2 = r1 - b2f(mu);
        unsigned short lu = f2bu(r2);
        unsigned short* row = Bcat + (size_t)n * KCAT + k;
        row[0]        = hu;
        row[KPAD]     = mu;
        row[2 * KPAD] = lu;
    }
}

// ---------------------------------------------------------------------------
// K1: convert fp32 binary spikes [rows][700] -> bf16 [rows][704] (exact).
// ---------------------------------------------------------------------------
__global__ __launch_bounds__(256) void k1_cvt(const float* __restrict__ A,
                                              unsigned short* __restrict__ Abf,
                                              int rows) {
    int idx = blockIdx.x * 256 + threadIdx.x;   // quad index: 176 per row
    int r = idx / 176, q = idx - r * 176;
    if (r >= rows) return;
    int k = q * 4;
    ushort4 o = make_ushort4(0, 0, 0, 0);
    if (k < NI) {  // k <= 696; 700 % 4 == 0 so full quad in range
        float4 v = *(const float4*)(A + (size_t)r * NI + k);
        o.x = f2bu(v.x); o.y = f2bu(v.y); o.z = f2bu(v.z); o.w = f2bu(v.w);
    }
    *(ushort4*)(Abf + (size_t)r * KPAD + k) = o;
}

// ---------------------------------------------------------------------------
// K2: fc1 via bf16 MFMA, 3-way split accumulated into one fp32 acc.
//   C[m,n] = sum_s sum_k A[m,k] * Bsplit_s[n,k]
//   128x128 tile, BK=32, 4 waves, 4x4 16x16x32 frags/wave.
//   LDS: As[128][32] + Bs[3][128][32] bf16 = 32 KB, global_load_lds width 16.
// ---------------------------------------------------------------------------
__global__ __launch_bounds__(256) void k2_fc1(const unsigned short* __restrict__ Abf,
                                              const unsigned short* __restrict__ Bcat,
                                              float* __restrict__ C) {
    __shared__ unsigned short As[128 * 32];
    __shared__ unsigned short Bs[3][128 * 32];
    const int tid  = threadIdx.x;
    const int lane = tid & 63;
    const int wv   = tid >> 6;
    const int bn   = blockIdx.x * 128;   // n-tile fast dim: 8 blocks share A panel
    const int brow = blockIdx.y * 128;
    const int wm   = (wv >> 1) * 64;
    const int wn   = (wv & 1) * 64;

    f32x4 acc[4][4];
#pragma unroll
    for (int i = 0; i < 4; ++i)
#pragma unroll
        for (int j = 0; j < 4; ++j) acc[i][j] = (f32x4){0.f, 0.f, 0.f, 0.f};

    // stage one 128x32 bf16 tile: 512 16B-chunks; wave wv, call j covers
    // chunks [wv*128 + j*64 + lane]; LDS dest = wave-uniform base + lane*16.
    auto stage = [&](const unsigned short* g, int growbase, int rstride, int kcol,
                     unsigned short* lds) {
#pragma unroll
        for (int j = 0; j < 2; ++j) {
            int c   = wv * 128 + j * 64 + lane;
            int row = c >> 2;
            int ks  = (c & 3) * 8;
            const unsigned short* src = g + (size_t)(growbase + row) * rstride + kcol + ks;
            __builtin_amdgcn_global_load_lds(
                (const __attribute__((address_space(1))) void*)src,
                (__attribute__((address_space(3))) void*)(lds + (wv * 128 + j * 64) * 8),
                16, 0, 0);
        }
    };

    for (int kt = 0; kt < KT_N; ++kt) {
        stage(Abf, brow, KPAD, kt * 32, As);
#pragma unroll
        for (int s = 0; s < 3; ++s)
            stage(Bcat, bn, KCAT, s * KPAD + kt * 32, Bs[s]);
        __syncthreads();

        bf16x8 a[4];
#pragma unroll
        for (int i = 0; i < 4; ++i)
            a[i] = *(const bf16x8*)&As[(wm + i * 16 + (lane & 15)) * 32 + (lane >> 4) * 8];
#pragma unroll
        for (int s = 0; s < 3; ++s) {
#pragma unroll
            for (int j = 0; j < 4; ++j) {
                bf16x8 b = *(const bf16x8*)&Bs[s][(wn + j * 16 + (lane & 15)) * 32 + (lane >> 4) * 8];
#pragma unroll
                for (int i = 0; i < 4; ++i)
                    acc[i][j] = __builtin_amdgcn_mfma_f32_16x16x32_bf16(a[i], b, acc[i][j], 0, 0, 0);
            }
        }
        __syncthreads();
    }

    // C/D layout: col = lane&15, row = (lane>>4)*4 + q   [m89/m91 verified]
#pragma unroll
    for (int i = 0; i < 4; ++i) {
#pragma unroll
        for (int j = 0; j < 4; ++j) {
            int col  = bn + wn + j * 16 + (lane & 15);
            int row0 = brow + wm + i * 16 + ((lane >> 4) << 2);
#pragma unroll
            for (int q = 0; q < 4; ++q)
                C[(size_t)(row0 + q) * NH + col] = acc[i][j][q];
        }
    }
}

// ---------------------------------------------------------------------------
// K3: LIF scan over a T-chunk. One thread per (b,h); spikes as ballot masks.
// ---------------------------------------------------------------------------
__global__ __launch_bounds__(256) void k3_lif(const float* __restrict__ cur1,
                                              float* __restrict__ mem1,
                                              unsigned long long* __restrict__ bits,
                                              int TC) {
    int b = blockIdx.x >> 2;
    int hg = blockIdx.x & 3;
    int h = hg * 256 + threadIdx.x;
    int w = threadIdx.x >> 6;
    float mem = mem1[b * NH + h];
    for (int tc = 0; tc < TC; ++tc) {
        float c = cur1[(tc * BATCH + b) * NH + h];
        float reset = (mem > 1.0f) ? 1.0f : 0.0f;
        mem = fmaf(BETAF, mem, c) - reset;
        bool spk = mem > 1.0f;
        unsigned long long msk = __ballot(spk);
        if ((threadIdx.x & 63) == 0)
            bits[(size_t)(tc * BATCH + b) * 16 + hg * 4 + w] = msk;
    }
    mem1[b * NH + h] = mem;
}

// ---------------------------------------------------------------------------
// K4: fc2 sparse gather over spike bitmasks. One wave per (t,b) row.
// ---------------------------------------------------------------------------
__global__ __launch_bounds__(256) void k4_fc2(const unsigned long long* __restrict__ bits,
                                              const float* __restrict__ W2T,
                                              float* __restrict__ cur2) {
    int row = blockIdx.x * 4 + (threadIdx.x >> 6);
    int lane = threadIdx.x & 63;
    unsigned long long mv = (lane < 16) ? bits[(size_t)row * 16 + lane] : 0ULL;
    float p = 0.f;
#pragma unroll 1
    for (int wseg = 0; wseg < 16; ++wseg) {
        unsigned long long m = __shfl(mv, wseg);
        while (m) {
            int bit = __ffsll((unsigned long long)m) - 1;
            m &= m - 1;
            int h = wseg * 64 + bit;
            if (lane < NO) p += W2T[h * NO + lane];
        }
    }
    if (lane < NO) cur2[(size_t)row * NO + lane] = p;
}

// ---------------------------------------------------------------------------
// K5: leaky readout (no reset) + softmax over 20 outputs.
// ---------------------------------------------------------------------------
__global__ __launch_bounds__(256) void k5_readout(const float* __restrict__ cur2,
                                                  float* __restrict__ out_mem,
                                                  float* __restrict__ out_sm) {
    int b = blockIdx.x * 8 + (threadIdx.x >> 5);
    int o = threadIdx.x & 31;
    bool act = o < NO;
    float mem = 0.f;
    for (int t = 0; t < T_STEPS; ++t) {
        int base = (t * BATCH + b) * NO;
        float c = act ? cur2[base + o] : 0.f;
        mem = fmaf(BETAF, mem, c);
        float mx = act ? mem : -3.4e38f;
#pragma unroll
        for (int off = 16; off; off >>= 1) mx = fmaxf(mx, __shfl_xor(mx, off, 32));
        float p = act ? expf(mem - mx) : 0.f;
        float s = p;
#pragma unroll
        for (int off = 16; off; off >>= 1) s += __shfl_xor(s, off, 32);
        if (act) {
            out_mem[base + o] = mem;
            out_sm[base + o] = p / s;
        }
    }
}

// ---------------------------------------------------------------------------
extern "C" void kernel_launch(void* const* d_in, const int* in_sizes, int n_in,
                              void* d_out, int out_size, void* d_ws, size_t ws_size,
                              hipStream_t stream) {
    const float* spikes = (const float*)d_in[0];   // [250,256,700]
    const float* W1     = (const float*)d_in[1];   // [1024,700]
    const float* W2     = (const float*)d_in[2];   // [20,1024]
    float* out_mem = (float*)d_out;                              // [250,256,20]
    float* out_sm  = out_mem + (size_t)T_STEPS * BATCH * NO;     // [250,256,20]

    char* ws = (char*)d_ws;
    size_t off = 0;
    auto alloc = [&](size_t bytes) -> char* {
        off = (off + 255) & ~(size_t)255;
        char* p = ws + off;
        off += bytes;
        return p;
    };
    float*          W2T  = (float*)alloc((size_t)NH * NO * 4);
    float*          mem1 = (float*)alloc((size_t)BATCH * NH * 4);
    float*          cur2 = (float*)alloc((size_t)T_STEPS * BATCH * NO * 4);
    unsigned short* Bcat = (unsigned short*)alloc((size_t)NH * KCAT * 2);

    // T-chunking: per step need cur1 (1 MB) + Abf (352 KB) + bits (32 KB).
    size_t fixed = (off + 255) & ~(size_t)255;
    size_t rem = ws_size > fixed ? ws_size - fixed : 0;
    size_t per_t = (size_t)BATCH * NH * 4 + (size_t)BATCH * KPAD * 2
                 + (size_t)BATCH * 16 * 8 + 768;
    int TC = (int)(rem / per_t);
    if (TC > T_STEPS) TC = T_STEPS;
    if (TC < 1) TC = 1;
    float*              cur1 = (float*)alloc((size_t)TC * BATCH * NH * 4);
    unsigned short*     Abf  = (unsigned short*)alloc((size_t)TC * BATCH * KPAD * 2);
    unsigned long long* bits = (unsigned long long*)alloc((size_t)TC * BATCH * 16 * 8);

    k0_init<<<(NH * KPAD + 255) / 256, 256, 0, stream>>>(W1, W2, W2T, mem1, Bcat);

    for (int t0 = 0; t0 < T_STEPS; t0 += TC) {
        int tc = T_STEPS - t0 < TC ? T_STEPS - t0 : TC;
        int rows = tc * BATCH;
        k1_cvt<<<(rows * 176 + 255) / 256, 256, 0, stream>>>(
            spikes + (size_t)t0 * BATCH * NI, Abf, rows);
        dim3 g2(8, rows / 128);   // n-tiles fast (A-panel L2 reuse), m-tiles slow
        k2_fc1<<<g2, 256, 0, stream>>>(Abf, Bcat, cur1);
        k3_lif<<<1024, 256, 0, stream>>>(cur1, mem1, bits, tc);
        k4_fc2<<<tc * 64, 256, 0, stream>>>(bits, W2T, cur2 + (size_t)t0 * BATCH * NO);
    }

    k5_readout<<<32, 256, 0, stream>>>(cur2, out_mem, out_sm);
}

// Round 3
// 613.640 us; speedup vs baseline: 2.3968x; 1.1396x over previous
//
#include <hip/hip_runtime.h>
#include <hip/hip_bf16.h>
#include <cstdint>

#define T_STEPS 250
#define BATCH   256
#define NI      700
#define NH      1024
#define NO      20
#define BETAF   0.9f
#define KPAD    704          // 22 * 32
#define KT_N    22
#define KCAT    2112         // 3 * KPAD

typedef __attribute__((ext_vector_type(8))) short bf16x8;
typedef __attribute__((ext_vector_type(4))) float f32x4;
typedef __attribute__((ext_vector_type(8))) unsigned short u16x8;

static __device__ __forceinline__ unsigned short f2bu(float x) {
    union { __hip_bfloat16 h; unsigned short u; } c;
    c.h = __float2bfloat16(x);
    return c.u;
}
static __device__ __forceinline__ float b2f(unsigned short u) {
    union { __hip_bfloat16 h; unsigned short u; } c;
    c.u = u;
    return __bfloat162float(c.h);
}

// ---------------------------------------------------------------------------
// K0: zero LIF state; W2T[h][o]; Bcat = [hi|mid|lo] bf16 split of W1,
//     padded K 700->704. Bcat[n][s*704+k].
// ---------------------------------------------------------------------------
__global__ __launch_bounds__(256) void k0_init(const float* __restrict__ W1,
                                               const float* __restrict__ W2,
                                               float* __restrict__ W2T,
                                               float* __restrict__ mem1,
                                               unsigned short* __restrict__ Bcat) {
    int idx = blockIdx.x * 256 + threadIdx.x;
    if (idx < BATCH * NH) mem1[idx] = 0.f;
    if (idx < NH * NO) {
        int h = idx / NO, o = idx % NO;
        W2T[idx] = W2[o * NH + h];
    }
    if (idx < NH * KPAD) {
        int n = idx / KPAD, k = idx % KPAD;
        float w = (k < NI) ? W1[n * NI + k] : 0.f;
        unsigned short hu = f2bu(w);
        float r1 = w - b2f(hu);
        unsigned short mu = f2bu(r1);
        float r2 = r1 - b2f(mu);
        unsigned short lu = f2bu(r2);
        unsigned short* row = Bcat + (size_t)n * KCAT + k;
        row[0]        = hu;
        row[KPAD]     = mu;
        row[2 * KPAD] = lu;
    }
}

// ---------------------------------------------------------------------------
// K2: fc1 via bf16 MFMA, 3-way split, cvt fused (reads raw fp32 spikes).
//   128x128 tile, BK=32, 4 waves, 48 MFMA / K-step.
//   LDS XOR-swizzle (slot ^= row&3 on 16B chunks):
//     A: reg-staged (load fp32 -> cvt bf16 -> swizzled ds_write_b128)
//     B: global_load_lds, linear dest + pre-swizzled per-lane SOURCE
//   Fragment reads apply the same XOR; row&3 == lane&3 for all frag rows.
//   XCD-grouping bid swizzle: 8 n-tiles of one m-tile land on one XCD.
// ---------------------------------------------------------------------------
__global__ __launch_bounds__(256) void k2_fc1(const float* __restrict__ A,
                                              const unsigned short* __restrict__ Bcat,
                                              float* __restrict__ C) {
    __shared__ unsigned short As[128 * 32];
    __shared__ unsigned short Bs[3][128 * 32];
    const int tid  = threadIdx.x;
    const int lane = tid & 63;
    const int wv   = tid >> 6;

    int nwg = gridDim.x, bid = blockIdx.x, w;
    if ((nwg & 7) == 0) w = (bid & 7) * (nwg >> 3) + (bid >> 3);
    else                w = bid;
    const int brow = (w >> 3) * 128;
    const int bn   = (w & 7) * 128;
    const int wm   = (wv >> 1) * 64;
    const int wn   = (wv & 1) * 64;

    f32x4 acc[4][4];
#pragma unroll
    for (int i = 0; i < 4; ++i)
#pragma unroll
        for (int j = 0; j < 4; ++j) acc[i][j] = (f32x4){0.f, 0.f, 0.f, 0.f};

    // ---- A reg-staging: thread -> (row = tid>>1, k-half = (tid&1)*16) ----
    const int arow = tid >> 1;
    const int ak0  = (tid & 1) * 16;
    const float* arowp = A + (size_t)(brow + arow) * NI;
    float4 ar[4];
    auto loadA = [&](int kt) {
#pragma unroll
        for (int i = 0; i < 4; ++i) {
            int kg = kt * 32 + ak0 + i * 4;
            ar[i] = (kg < NI) ? *(const float4*)(arowp + kg)
                              : make_float4(0.f, 0.f, 0.f, 0.f);
        }
    };
    const int asl0 = ((tid & 1) * 2) ^ (arow & 3);   // swizzled slot of chunk 0
    const int asl1 = ((tid & 1) * 2 + 1) ^ (arow & 3);
    auto writeA = [&]() {
        u16x8 lo, hi;
        lo[0] = f2bu(ar[0].x); lo[1] = f2bu(ar[0].y); lo[2] = f2bu(ar[0].z); lo[3] = f2bu(ar[0].w);
        lo[4] = f2bu(ar[1].x); lo[5] = f2bu(ar[1].y); lo[6] = f2bu(ar[1].z); lo[7] = f2bu(ar[1].w);
        hi[0] = f2bu(ar[2].x); hi[1] = f2bu(ar[2].y); hi[2] = f2bu(ar[2].z); hi[3] = f2bu(ar[2].w);
        hi[4] = f2bu(ar[3].x); hi[5] = f2bu(ar[3].y); hi[6] = f2bu(ar[3].z); hi[7] = f2bu(ar[3].w);
        *(u16x8*)&As[arow * 32 + asl0 * 8] = lo;
        *(u16x8*)&As[arow * 32 + asl1 * 8] = hi;
    };

    // ---- B staging: gload_lds, linear dest, swizzled per-lane source ----
    const int gsl = ((lane & 3) ^ ((lane >> 2) & 3)) * 8;  // element offset
    auto stageB = [&](int kt) {
#pragma unroll
        for (int s = 0; s < 3; ++s)
#pragma unroll
            for (int j = 0; j < 2; ++j) {
                int c   = wv * 128 + j * 64 + lane;
                int row = c >> 2;
                const unsigned short* src =
                    Bcat + (size_t)(bn + row) * KCAT + s * KPAD + kt * 32 + gsl;
                __builtin_amdgcn_global_load_lds(
                    (const __attribute__((address_space(1))) void*)src,
                    (__attribute__((address_space(3))) void*)(Bs[s] + (wv * 128 + j * 64) * 8),
                    16, 0, 0);
            }
    };

    const int frow = lane & 15;
    const int fsl  = ((lane >> 4) ^ (lane & 3)) * 8;   // swizzled frag slot

    loadA(0);
    for (int kt = 0; kt < KT_N; ++kt) {
        __syncthreads();                 // prev compute done reading LDS
        writeA();
        stageB(kt);
        if (kt + 1 < KT_N) loadA(kt + 1);   // in flight across compute
        __syncthreads();                 // vmcnt/lgkm drain: tiles ready

        bf16x8 a[4];
#pragma unroll
        for (int i = 0; i < 4; ++i)
            a[i] = *(const bf16x8*)&As[(wm + i * 16 + frow) * 32 + fsl];
#pragma unroll
        for (int s = 0; s < 3; ++s) {
#pragma unroll
            for (int j = 0; j < 4; ++j) {
                bf16x8 b = *(const bf16x8*)&Bs[s][(wn + j * 16 + frow) * 32 + fsl];
#pragma unroll
                for (int i = 0; i < 4; ++i)
                    acc[i][j] = __builtin_amdgcn_mfma_f32_16x16x32_bf16(a[i], b, acc[i][j], 0, 0, 0);
            }
        }
    }

    // C/D layout: col = lane&15, row = (lane>>4)*4 + q
#pragma unroll
    for (int i = 0; i < 4; ++i) {
#pragma unroll
        for (int j = 0; j < 4; ++j) {
            int col  = bn + wn + j * 16 + (lane & 15);
            int row0 = brow + wm + i * 16 + ((lane >> 4) << 2);
#pragma unroll
            for (int q = 0; q < 4; ++q)
                C[(size_t)(row0 + q) * NH + col] = acc[i][j][q];
        }
    }
}

// ---------------------------------------------------------------------------
// K3: LIF scan, 4-deep explicit prefetch (named regs, static indexing).
// ---------------------------------------------------------------------------
__global__ __launch_bounds__(256) void k3_lif(const float* __restrict__ cur1,
                                              float* __restrict__ mem1,
                                              unsigned long long* __restrict__ bits,
                                              int TC) {
    int b = blockIdx.x >> 2;
    int hg = blockIdx.x & 3;
    int h = hg * 256 + threadIdx.x;
    const size_t S = (size_t)BATCH * NH;
    const float* p = cur1 + (size_t)b * NH + h;
    unsigned long long* bp = bits + (size_t)b * 16 + hg * 4 + (threadIdx.x >> 6);
    const bool lead = (threadIdx.x & 63) == 0;
    float mem = mem1[b * NH + h];

#define LIF_STEP(cv, t)                                                        \
    {                                                                          \
        float reset = (mem > 1.0f) ? 1.0f : 0.0f;                              \
        mem = fmaf(BETAF, mem, (cv)) - reset;                                  \
        unsigned long long mk = __ballot(mem > 1.0f);                          \
        if (lead) bp[(size_t)(t) * (BATCH * 16)] = mk;                         \
    }

    float c0 = (0 < TC) ? p[0] : 0.f;
    float c1 = (1 < TC) ? p[S] : 0.f;
    float c2 = (2 < TC) ? p[2 * S] : 0.f;
    float c3 = (3 < TC) ? p[3 * S] : 0.f;
    int tc = 0;
    for (; tc + 4 <= TC; tc += 4) {
        LIF_STEP(c0, tc + 0); if (tc + 4 < TC) c0 = p[(size_t)(tc + 4) * S];
        LIF_STEP(c1, tc + 1); if (tc + 5 < TC) c1 = p[(size_t)(tc + 5) * S];
        LIF_STEP(c2, tc + 2); if (tc + 6 < TC) c2 = p[(size_t)(tc + 6) * S];
        LIF_STEP(c3, tc + 3); if (tc + 7 < TC) c3 = p[(size_t)(tc + 7) * S];
    }
    for (; tc < TC; ++tc) { float c = p[(size_t)tc * S]; LIF_STEP(c, tc); }
#undef LIF_STEP
    mem1[b * NH + h] = mem;
}

// ---------------------------------------------------------------------------
// K4: fc2 sparse gather over spike bitmasks. One wave per (t,b) row.
// ---------------------------------------------------------------------------
__global__ __launch_bounds__(256) void k4_fc2(const unsigned long long* __restrict__ bits,
                                              const float* __restrict__ W2T,
                                              float* __restrict__ cur2) {
    int row = blockIdx.x * 4 + (threadIdx.x >> 6);
    int lane = threadIdx.x & 63;
    unsigned long long mv = (lane < 16) ? bits[(size_t)row * 16 + lane] : 0ULL;
    float p = 0.f;
#pragma unroll 1
    for (int wseg = 0; wseg < 16; ++wseg) {
        unsigned long long m = __shfl(mv, wseg);
        while (m) {
            int bit = __ffsll((unsigned long long)m) - 1;
            m &= m - 1;
            int h = wseg * 64 + bit;
            if (lane < NO) p += W2T[h * NO + lane];
        }
    }
    if (lane < NO) cur2[(size_t)row * NO + lane] = p;
}

// ---------------------------------------------------------------------------
// K5: leaky readout + softmax. No max-subtract (|mem| <= ~4, identical
//     mathematically), one-ahead prefetch, fast exp/div.
// ---------------------------------------------------------------------------
__global__ __launch_bounds__(256) void k5_readout(const float* __restrict__ cur2,
                                                  float* __restrict__ out_mem,
                                                  float* __restrict__ out_sm) {
    int b = blockIdx.x * 8 + (threadIdx.x >> 5);
    int o = threadIdx.x & 31;
    bool act = o < NO;
    const float* p = cur2 + (size_t)b * NO + (act ? o : 0);
    float mem = 0.f;
    float nxt = p[0];
    for (int t = 0; t < T_STEPS; ++t) {
        float c = nxt;
        if (t + 1 < T_STEPS) nxt = p[(size_t)(t + 1) * BATCH * NO];
        mem = fmaf(BETAF, mem, c);
        float e = act ? __expf(mem) : 0.f;
        float s = e;
#pragma unroll
        for (int off = 16; off; off >>= 1) s += __shfl_xor(s, off, 32);
        if (act) {
            int base = (t * BATCH + b) * NO;
            out_mem[base + o] = mem;
            out_sm[base + o] = __fdividef(e, s);
        }
    }
}

// ---------------------------------------------------------------------------
extern "C" void kernel_launch(void* const* d_in, const int* in_sizes, int n_in,
                              void* d_out, int out_size, void* d_ws, size_t ws_size,
                              hipStream_t stream) {
    const float* spikes = (const float*)d_in[0];   // [250,256,700]
    const float* W1     = (const float*)d_in[1];   // [1024,700]
    const float* W2     = (const float*)d_in[2];   // [20,1024]
    float* out_mem = (float*)d_out;                              // [250,256,20]
    float* out_sm  = out_mem + (size_t)T_STEPS * BATCH * NO;     // [250,256,20]

    char* ws = (char*)d_ws;
    size_t off = 0;
    auto alloc = [&](size_t bytes) -> char* {
        off = (off + 255) & ~(size_t)255;
        char* p = ws + off;
        off += bytes;
        return p;
    };
    float*          W2T  = (float*)alloc((size_t)NH * NO * 4);
    float*          mem1 = (float*)alloc((size_t)BATCH * NH * 4);
    float*          cur2 = (float*)alloc((size_t)T_STEPS * BATCH * NO * 4);
    unsigned short* Bcat = (unsigned short*)alloc((size_t)NH * KCAT * 2);

    // T-chunking: per step need cur1 (1 MB) + bits (32 KB).
    size_t fixed = (off + 255) & ~(size_t)255;
    size_t rem = ws_size > fixed ? ws_size - fixed : 0;
    size_t per_t = (size_t)BATCH * NH * 4 + (size_t)BATCH * 16 * 8 + 512;
    int TC = (int)(rem / per_t);
    if (TC > T_STEPS) TC = T_STEPS;
    if (TC < 1) TC = 1;
    float*              cur1 = (float*)alloc((size_t)TC * BATCH * NH * 4);
    unsigned long long* bits = (unsigned long long*)alloc((size_t)TC * BATCH * 16 * 8);

    k0_init<<<(NH * KPAD + 255) / 256, 256, 0, stream>>>(W1, W2, W2T, mem1, Bcat);

    for (int t0 = 0; t0 < T_STEPS; t0 += TC) {
        int tc = T_STEPS - t0 < TC ? T_STEPS - t0 : TC;
        int rows = tc * BATCH;
        int nwg = (rows / 128) * 8;
        k2_fc1<<<nwg, 256, 0, stream>>>(spikes + (size_t)t0 * BATCH * NI, Bcat, cur1);
        k3_lif<<<1024, 256, 0, stream>>>(cur1, mem1, bits, tc);
        k4_fc2<<<tc * 64, 256, 0, stream>>>(bits, W2T, cur2 + (size_t)t0 * BATCH * NO);
    }

    k5_readout<<<32, 256, 0, stream>>>(cur2, out_mem, out_sm);
}

// Round 4
// 528.142 us; speedup vs baseline: 2.7848x; 1.1619x over previous
//
#include <hip/hip_runtime.h>
#include <hip/hip_bf16.h>
#include <cstdint>

#define T_STEPS 250
#define BATCH   256
#define NI      700
#define NH      1024
#define NO      20
#define BETAF   0.9f
#define KPAD    704          // 22 * 32
#define KT_N    22
#define KCAT    2112         // 3 * KPAD

typedef __attribute__((ext_vector_type(8))) short bf16x8;
typedef __attribute__((ext_vector_type(4))) float f32x4;

static __device__ __forceinline__ unsigned short f2bu(float x) {
    union { __hip_bfloat16 h; unsigned short u; } c;
    c.h = __float2bfloat16(x);
    return c.u;
}
static __device__ __forceinline__ float b2f(unsigned short u) {
    union { __hip_bfloat16 h; unsigned short u; } c;
    c.u = u;
    return __bfloat162float(c.h);
}

// ---------------------------------------------------------------------------
// K0: zero LIF state; W2T[h][o]; Bcat = [hi|mid|lo] bf16 split of W1,
//     padded K 700->704. Bcat[n][s*704+k]. (linear; swizzle applied at k2's
//     per-lane gload_lds SOURCE address — rule 21.)
// ---------------------------------------------------------------------------
__global__ __launch_bounds__(256) void k0_init(const float* __restrict__ W1,
                                               const float* __restrict__ W2,
                                               float* __restrict__ W2T,
                                               float* __restrict__ mem1,
                                               unsigned short* __restrict__ Bcat) {
    int idx = blockIdx.x * 256 + threadIdx.x;
    if (idx < BATCH * NH) mem1[idx] = 0.f;
    if (idx < NH * NO) {
        int h = idx / NO, o = idx % NO;
        W2T[idx] = W2[o * NH + h];
    }
    if (idx < NH * KPAD) {
        int n = idx / KPAD, k = idx % KPAD;
        float w = (k < NI) ? W1[n * NI + k] : 0.f;
        unsigned short hu = f2bu(w);
        float r1 = w - b2f(hu);
        unsigned short mu = f2bu(r1);
        float r2 = r1 - b2f(mu);
        unsigned short lu = f2bu(r2);
        unsigned short* row = Bcat + (size_t)n * KCAT + k;
        row[0]        = hu;
        row[KPAD]     = mu;
        row[2 * KPAD] = lu;
    }
}

// ---------------------------------------------------------------------------
// K1: convert fp32 binary spikes [rows][700] -> bf16 [rows][704] (exact).
// ---------------------------------------------------------------------------
__global__ __launch_bounds__(256) void k1_cvt(const float* __restrict__ A,
                                              unsigned short* __restrict__ Abf,
                                              int rows) {
    int idx = blockIdx.x * 256 + threadIdx.x;   // quad index: 176 per row
    int r = idx / 176, q = idx - r * 176;
    if (r >= rows) return;
    int k = q * 4;
    ushort4 o = make_ushort4(0, 0, 0, 0);
    if (k < NI) {  // k <= 696; 700 % 4 == 0 so full quad in range
        float4 v = *(const float4*)(A + (size_t)r * NI + k);
        o.x = f2bu(v.x); o.y = f2bu(v.y); o.z = f2bu(v.z); o.w = f2bu(v.w);
    }
    *(ushort4*)(Abf + (size_t)r * KPAD + k) = o;
}

// ---------------------------------------------------------------------------
// K2: fc1 via bf16 MFMA, 3-way split accumulated into one fp32 acc.
//   R2-proven structure: all staging via global_load_lds, one drain/K-step.
//   128x128 tile, BK=32, 4 waves, 48 MFMA / K-step, 32 KB LDS.
//   LDS swizzle (both tiles, [128 rows][4 x 16B chunks]):
//     physical chunk p of row r holds logical chunk p ^ ((r>>1)&3).
//     Bank base = 16*(r&1) + 4*(p) -> consecutive rows spread over all 8
//     4-bank groups; frag reads are 2 lanes/bank (free).
//   Staged with linear LDS dest + pre-swizzled per-lane SOURCE (rule 21).
//   XCD-grouping bid swizzle: 8 n-tiles of one m-panel land on one XCD.
// ---------------------------------------------------------------------------
__global__ __launch_bounds__(256) void k2_fc1(const unsigned short* __restrict__ Abf,
                                              const unsigned short* __restrict__ Bcat,
                                              float* __restrict__ C) {
    __shared__ unsigned short As[128 * 32];
    __shared__ unsigned short Bs[3][128 * 32];
    const int tid  = threadIdx.x;
    const int lane = tid & 63;
    const int wv   = tid >> 6;

    int nwg = gridDim.x, bid = blockIdx.x, w;
    if ((nwg & 7) == 0) w = (bid & 7) * (nwg >> 3) + (bid >> 3);
    else                w = bid;
    const int brow = (w >> 3) * 128;
    const int bn   = (w & 7) * 128;
    const int wm   = (wv >> 1) * 64;
    const int wn   = (wv & 1) * 64;

    f32x4 acc[4][4];
#pragma unroll
    for (int i = 0; i < 4; ++i)
#pragma unroll
        for (int j = 0; j < 4; ++j) acc[i][j] = (f32x4){0.f, 0.f, 0.f, 0.f};

    // stage one 128x32 bf16 tile: 512 16B chunks; LDS dest is wave-uniform
    // base + lane*16 (linear); source column pre-swizzled per lane.
    auto stage = [&](const unsigned short* gbase, int rstride, int kcol,
                     unsigned short* lds) {
#pragma unroll
        for (int j = 0; j < 2; ++j) {
            int c   = wv * 128 + j * 64 + lane;
            int row = c >> 2;
            int lk  = ((c & 3) ^ ((row >> 1) & 3)) * 8;   // logical chunk for this slot
            const unsigned short* src = gbase + (size_t)row * rstride + kcol + lk;
            __builtin_amdgcn_global_load_lds(
                (const __attribute__((address_space(1))) void*)src,
                (__attribute__((address_space(3))) void*)(lds + (wv * 128 + j * 64) * 8),
                16, 0, 0);
        }
    };

    const unsigned short* Ab = Abf + (size_t)brow * KPAD;
    const unsigned short* Bb = Bcat + (size_t)bn * KCAT;

    const int frow = lane & 15;
    const int fsl  = (((lane >> 4) & 3) ^ ((frow >> 1) & 3)) * 8;  // swizzled frag slot

    for (int kt = 0; kt < KT_N; ++kt) {
        stage(Ab, KPAD, kt * 32, As);
#pragma unroll
        for (int s = 0; s < 3; ++s)
            stage(Bb, KCAT, s * KPAD + kt * 32, Bs[s]);
        __syncthreads();

        bf16x8 a[4];
#pragma unroll
        for (int i = 0; i < 4; ++i)
            a[i] = *(const bf16x8*)&As[(wm + i * 16 + frow) * 32 + fsl];
#pragma unroll
        for (int s = 0; s < 3; ++s) {
#pragma unroll
            for (int j = 0; j < 4; ++j) {
                bf16x8 b = *(const bf16x8*)&Bs[s][(wn + j * 16 + frow) * 32 + fsl];
#pragma unroll
                for (int i = 0; i < 4; ++i)
                    acc[i][j] = __builtin_amdgcn_mfma_f32_16x16x32_bf16(a[i], b, acc[i][j], 0, 0, 0);
            }
        }
        __syncthreads();
    }

    // C/D layout: col = lane&15, row = (lane>>4)*4 + q
#pragma unroll
    for (int i = 0; i < 4; ++i) {
#pragma unroll
        for (int j = 0; j < 4; ++j) {
            int col  = bn + wn + j * 16 + (lane & 15);
            int row0 = brow + wm + i * 16 + ((lane >> 4) << 2);
#pragma unroll
            for (int q = 0; q < 4; ++q)
                C[(size_t)(row0 + q) * NH + col] = acc[i][j][q];
        }
    }
}

// ---------------------------------------------------------------------------
// K3: LIF scan, 4-deep explicit prefetch (named regs, static indexing).
// ---------------------------------------------------------------------------
__global__ __launch_bounds__(256) void k3_lif(const float* __restrict__ cur1,
                                              float* __restrict__ mem1,
                                              unsigned long long* __restrict__ bits,
                                              int TC) {
    int b = blockIdx.x >> 2;
    int hg = blockIdx.x & 3;
    int h = hg * 256 + threadIdx.x;
    const size_t S = (size_t)BATCH * NH;
    const float* p = cur1 + (size_t)b * NH + h;
    unsigned long long* bp = bits + (size_t)b * 16 + hg * 4 + (threadIdx.x >> 6);
    const bool lead = (threadIdx.x & 63) == 0;
    float mem = mem1[b * NH + h];

#define LIF_STEP(cv, t)                                                        \
    {                                                                          \
        float reset = (mem > 1.0f) ? 1.0f : 0.0f;                              \
        mem = fmaf(BETAF, mem, (cv)) - reset;                                  \
        unsigned long long mk = __ballot(mem > 1.0f);                          \
        if (lead) bp[(size_t)(t) * (BATCH * 16)] = mk;                         \
    }

    float c0 = (0 < TC) ? p[0] : 0.f;
    float c1 = (1 < TC) ? p[S] : 0.f;
    float c2 = (2 < TC) ? p[2 * S] : 0.f;
    float c3 = (3 < TC) ? p[3 * S] : 0.f;
    int tc = 0;
    for (; tc + 4 <= TC; tc += 4) {
        LIF_STEP(c0, tc + 0); if (tc + 4 < TC) c0 = p[(size_t)(tc + 4) * S];
        LIF_STEP(c1, tc + 1); if (tc + 5 < TC) c1 = p[(size_t)(tc + 5) * S];
        LIF_STEP(c2, tc + 2); if (tc + 6 < TC) c2 = p[(size_t)(tc + 6) * S];
        LIF_STEP(c3, tc + 3); if (tc + 7 < TC) c3 = p[(size_t)(tc + 7) * S];
    }
    for (; tc < TC; ++tc) { float c = p[(size_t)tc * S]; LIF_STEP(c, tc); }
#undef LIF_STEP
    mem1[b * NH + h] = mem;
}

// ---------------------------------------------------------------------------
// K4: fc2 sparse gather over spike bitmasks. One wave per (t,b) row.
// ---------------------------------------------------------------------------
__global__ __launch_bounds__(256) void k4_fc2(const unsigned long long* __restrict__ bits,
                                              const float* __restrict__ W2T,
                                              float* __restrict__ cur2) {
    int row = blockIdx.x * 4 + (threadIdx.x >> 6);
    int lane = threadIdx.x & 63;
    unsigned long long mv = (lane < 16) ? bits[(size_t)row * 16 + lane] : 0ULL;
    float p = 0.f;
#pragma unroll 1
    for (int wseg = 0; wseg < 16; ++wseg) {
        unsigned long long m = __shfl(mv, wseg);
        while (m) {
            int bit = __ffsll((unsigned long long)m) - 1;
            m &= m - 1;
            int h = wseg * 64 + bit;
            if (lane < NO) p += W2T[h * NO + lane];
        }
    }
    if (lane < NO) cur2[(size_t)row * NO + lane] = p;
}

// ---------------------------------------------------------------------------
// K5: leaky readout + softmax. No max-subtract (|mem| bounded, identical
//     mathematically), one-ahead prefetch, fast exp/div.
// ---------------------------------------------------------------------------
__global__ __launch_bounds__(256) void k5_readout(const float* __restrict__ cur2,
                                                  float* __restrict__ out_mem,
                                                  float* __restrict__ out_sm) {
    int b = blockIdx.x * 8 + (threadIdx.x >> 5);
    int o = threadIdx.x & 31;
    bool act = o < NO;
    const float* p = cur2 + (size_t)b * NO + (act ? o : 0);
    float mem = 0.f;
    float nxt = p[0];
    for (int t = 0; t < T_STEPS; ++t) {
        float c = nxt;
        if (t + 1 < T_STEPS) nxt = p[(size_t)(t + 1) * BATCH * NO];
        mem = fmaf(BETAF, mem, c);
        float e = act ? __expf(mem) : 0.f;
        float s = e;
#pragma unroll
        for (int off = 16; off; off >>= 1) s += __shfl_xor(s, off, 32);
        if (act) {
            int base = (t * BATCH + b) * NO;
            out_mem[base + o] = mem;
            out_sm[base + o] = __fdividef(e, s);
        }
    }
}

// ---------------------------------------------------------------------------
extern "C" void kernel_launch(void* const* d_in, const int* in_sizes, int n_in,
                              void* d_out, int out_size, void* d_ws, size_t ws_size,
                              hipStream_t stream) {
    const float* spikes = (const float*)d_in[0];   // [250,256,700]
    const float* W1     = (const float*)d_in[1];   // [1024,700]
    const float* W2     = (const float*)d_in[2];   // [20,1024]
    float* out_mem = (float*)d_out;                              // [250,256,20]
    float* out_sm  = out_mem + (size_t)T_STEPS * BATCH * NO;     // [250,256,20]

    char* ws = (char*)d_ws;
    size_t off = 0;
    auto alloc = [&](size_t bytes) -> char* {
        off = (off + 255) & ~(size_t)255;
        char* p = ws + off;
        off += bytes;
        return p;
    };
    float*          W2T  = (float*)alloc((size_t)NH * NO * 4);
    float*          mem1 = (float*)alloc((size_t)BATCH * NH * 4);
    float*          cur2 = (float*)alloc((size_t)T_STEPS * BATCH * NO * 4);
    unsigned short* Bcat = (unsigned short*)alloc((size_t)NH * KCAT * 2);

    // T-chunking: per step need cur1 (1 MB) + Abf (352 KB) + bits (32 KB).
    size_t fixed = (off + 255) & ~(size_t)255;
    size_t rem = ws_size > fixed ? ws_size - fixed : 0;
    size_t per_t = (size_t)BATCH * NH * 4 + (size_t)BATCH * KPAD * 2
                 + (size_t)BATCH * 16 * 8 + 768;
    int TC = (int)(rem / per_t);
    if (TC > T_STEPS) TC = T_STEPS;
    if (TC < 1) TC = 1;
    float*              cur1 = (float*)alloc((size_t)TC * BATCH * NH * 4);
    unsigned short*     Abf  = (unsigned short*)alloc((size_t)TC * BATCH * KPAD * 2);
    unsigned long long* bits = (unsigned long long*)alloc((size_t)TC * BATCH * 16 * 8);

    k0_init<<<(NH * KPAD + 255) / 256, 256, 0, stream>>>(W1, W2, W2T, mem1, Bcat);

    for (int t0 = 0; t0 < T_STEPS; t0 += TC) {
        int tc = T_STEPS - t0 < TC ? T_STEPS - t0 : TC;
        int rows = tc * BATCH;
        k1_cvt<<<(rows * 176 + 255) / 256, 256, 0, stream>>>(
            spikes + (size_t)t0 * BATCH * NI, Abf, rows);
        int nwg = (rows / 128) * 8;
        k2_fc1<<<nwg, 256, 0, stream>>>(Abf, Bcat, cur1);
        k3_lif<<<1024, 256, 0, stream>>>(cur1, mem1, bits, tc);
        k4_fc2<<<tc * 64, 256, 0, stream>>>(bits, W2T, cur2 + (size_t)t0 * BATCH * NO);
    }

    k5_readout<<<32, 256, 0, stream>>>(cur2, out_mem, out_sm);
}